// Round 14
// baseline (1358.061 us; speedup 1.0000x reference)
//
#include <hip/hip_runtime.h>
#include <hip/hip_bf16.h>
#include <hip/hip_cooperative_groups.h>

namespace cg = cooperative_groups;

// Problem constants
#define BB 2
#define SS 2048
#define DD 128
#define HH 8
#define HDIM 16
#define DF 512
#define SPK 36        // attn P stride (shorts); 72B rows
#define HS 520        // fallback ffn LDS h stride
#define LNS 136       // fallback LN LDS stride
#define GRID 2048

typedef float floatx4 __attribute__((ext_vector_type(4)));
typedef float floatx16 __attribute__((ext_vector_type(16)));
typedef short frag8 __attribute__((ext_vector_type(8)));

__device__ __forceinline__ short f2bf(float x) {
  union { __hip_bfloat16 h; short s; } u;
  u.h = __float2bfloat16(x);
  return u.s;
}
__device__ __forceinline__ unsigned int pkbf(float a, float b) {
  float2 f; f.x = a; f.y = b;
  union { __hip_bfloat162 h2; unsigned int u; } u;
  u.h2 = __float22bfloat162_rn(f);
  return u.u;
}
__device__ __forceinline__ frag8 cvt8(const float4 a, const float4 b) {
  union { frag8 f; unsigned int u[4]; } x;
  x.u[0] = pkbf(a.x, a.y);
  x.u[1] = pkbf(a.z, a.w);
  x.u[2] = pkbf(b.x, b.y);
  x.u[3] = pkbf(b.z, b.w);
  return x.f;
}

struct Params {
  const float* src[10];  // self_wq,self_wk,self_wv,cross_wq,cross_wk,cross_wv,w1,w2,w3,w4
  const float* x_tgt;
  const float* enc_out;
  const float* b1; const float* b2; const float* b3; const float* b4;
  short* wt;
  short* Qs; short* Ks; short* Vts; short* AMs;
  short* Qc; short* Kc; short* Vtc; short* AMc;
  float* R2; short* LN; short* Hb;
  float* Out;
};

union SharedU {
  short sC[4][16 * 130];          // qkv phase: per-wave C staging (16.6 KB)
  struct {                        // attn phase (18.2 KB)
    short sP[4][32 * SPK];
    float pnum[4][16 * 33];
    float pl[4][32];
  } at;
  struct {                        // tailA phase (0.5 KB)
    float sumS[4][16];
    float sumQ[4][16];
  } tl;
};

// =====================================================================
// Cooperative mega-kernel: wprep | qkv | attn | gemm12+norm | ffn1 | ffn2
// grid 2048 x 256; __launch_bounds__(256,8) caps VGPR at 64 so all
// 8 blocks/CU are co-resident (required for grid.sync).
// =====================================================================
__global__ __launch_bounds__(256, 8) void mega_kernel(Params p) {
  cg::grid_group grid = cg::this_grid();
  __shared__ SharedU sh;

  const int t = threadIdx.x, wid = t >> 6, lane = t & 63;
  const int quad16 = lane >> 4, l16 = lane & 15;

  // ---------------- P0: weight prep (WT[n][k] bf16, scales folded) ----------
  {
    const int idx = blockIdx.x * 256 + t;
    if (idx < 262144) {
      int wi, base;
      if (idx < 131072)      { wi = idx >> 14; base = wi << 14; }
      else if (idx < 196608) { wi = 8; base = 131072; }
      else                   { wi = 9; base = 196608; }
      const int local = idx - base;
      const int kshift = (wi == 9) ? 9 : 7;
      const int N = (wi == 8) ? 512 : 128;
      const int K = 1 << kshift;
      const int n = local >> kshift, k = local & (K - 1);
      const float sc = (wi == 0 || wi == 3) ? 0.25f * 1.4426950408889634f : 1.0f;
      p.wt[idx] = f2bf(p.src[wi][k * N + n] * sc);
    }
  }
  grid.sync();

  // ---------------- P1: QKV projections (1536 single-wave tasks) ------------
  {
    const int g = blockIdx.x * 4 + wid;
    if (g < 1536) {
      const int which = g % 6;
      const int mtile = g / 6;
      const int kind = which % 3;  // 0=Q,1=K,2=Vt
      const int mbase = mtile * 16;
      const float* A = (which == 3) ? p.enc_out : p.x_tgt;
      const short* W = p.wt + which * 16384;
      short* Qb = (which < 3) ? p.Qs : p.Qc;
      short* Kb = (which < 3) ? p.Ks : p.Kc;
      short* Vtb = (which < 3) ? p.Vts : p.Vtc;
      short* sCw = sh.sC[wid];

      floatx4 acc[8];
#pragma unroll
      for (int ct = 0; ct < 8; ct++) acc[ct] = (floatx4){0.f, 0.f, 0.f, 0.f};
#pragma unroll
      for (int ks = 0; ks < 4; ks++) {
        const float4* ar = (const float4*)&A[(size_t)(mbase + l16) * DD + ks * 32 + quad16 * 8];
        const frag8 af = cvt8(ar[0], ar[1]);
#pragma unroll
        for (int ct = 0; ct < 8; ct++) {
          const frag8 bf = *(const frag8*)&W[(ct * 16 + l16) * DD + ks * 32 + quad16 * 8];
          acc[ct] = __builtin_amdgcn_mfma_f32_16x16x32_bf16(af, bf, acc[ct], 0, 0, 0);
        }
      }
#pragma unroll
      for (int ct = 0; ct < 8; ct++) {
#pragma unroll
        for (int r = 0; r < 4; r++) {
          sCw[(quad16 * 4 + r) * 130 + ct * 16 + l16] = f2bf(acc[ct][r]);
        }
      }
      // wave-private LDS slice: in-order DS per wave, no barrier needed
      const int b = mbase >> 11;
      const int sbase = mbase & 2047;
      if (kind <= 1) {
        short* Dst = (kind == 0) ? Qb : Kb;
        const int s = lane >> 2, c4 = lane & 3;
#pragma unroll
        for (int h = 0; h < 8; h++) {
          short4 v;  // split quirk: n = dci*8 + h
          v.x = sCw[s * 130 + (c4 * 4 + 0) * 8 + h];
          v.y = sCw[s * 130 + (c4 * 4 + 1) * 8 + h];
          v.z = sCw[s * 130 + (c4 * 4 + 2) * 8 + h];
          v.w = sCw[s * 130 + (c4 * 4 + 3) * 8 + h];
          const int bh = b * HH + h;
          *(short4*)&Dst[((size_t)bh * SS + sbase + s) * HDIM + c4 * 4] = v;
        }
      } else {
        const int dci = lane >> 2, c4 = lane & 3;
#pragma unroll
        for (int h = 0; h < 8; h++) {
          short4 v;
          v.x = sCw[(c4 * 4 + 0) * 130 + dci * 8 + h];
          v.y = sCw[(c4 * 4 + 1) * 130 + dci * 8 + h];
          v.z = sCw[(c4 * 4 + 2) * 130 + dci * 8 + h];
          v.w = sCw[(c4 * 4 + 3) * 130 + dci * 8 + h];
          const int bh = b * HH + h;
          *(short4*)&Vtb[((size_t)bh * HDIM + dci) * SS + sbase + c4 * 4] = v;
        }
      }
    }
  }
  grid.sync();

  // ---------------- P2: attention (r13 code; 1:1 block-task) ----------------
  {
    const int l32 = lane & 31, half = lane >> 5;
    const int qbase = (blockIdx.x & 63) * 32;
    const int bh = (blockIdx.x >> 6) & 15;
    const int inst = blockIdx.x >> 10;
    const short* Q = inst ? p.Qc : p.Qs;
    const short* K = inst ? p.Kc : p.Ks;
    const short* Vt = inst ? p.Vtc : p.Vts;
    short* AM = inst ? p.AMc : p.AMs;
    const size_t headoff = (size_t)bh * SS;

    const frag8 qf = *(const frag8*)&Q[(headoff + qbase + l32) * HDIM + half * 8];
    frag8 onef;
#pragma unroll
    for (int i = 0; i < 8; i++) onef[i] = (short)0x3f80;

    floatx4 acc_o[2], acc_l[2];
    acc_o[0] = (floatx4){0.f, 0.f, 0.f, 0.f}; acc_o[1] = acc_o[0];
    acc_l[0] = acc_o[0]; acc_l[1] = acc_o[0];

    const int keyw = wid * 512;
    const short* Kp = K + (headoff + l32) * HDIM + half * 8;
    const short* Vp = Vt + ((size_t)bh * HDIM + l16) * SS + quad16 * 8;

    frag8 kf = *(const frag8*)&Kp[(size_t)keyw * HDIM];
    frag8 vf = *(const frag8*)&Vp[keyw];

#pragma unroll 1
    for (int it = 0; it < 16; it++) {
      const int nb = keyw + ((it + 1 < 16) ? (it + 1) : 15) * 32;
      const frag8 kf_n = *(const frag8*)&Kp[(size_t)nb * HDIM];
      const frag8 vf_n = *(const frag8*)&Vp[nb];

      const floatx16 z16 = {0.f};
      const floatx16 sc = __builtin_amdgcn_mfma_f32_32x32x16_bf16(kf, qf, z16, 0, 0, 0);
#pragma unroll
      for (int g = 0; g < 4; g++) {
        const float e0 = __builtin_amdgcn_exp2f(sc[4 * g + 0]);
        const float e1 = __builtin_amdgcn_exp2f(sc[4 * g + 1]);
        const float e2 = __builtin_amdgcn_exp2f(sc[4 * g + 2]);
        const float e3 = __builtin_amdgcn_exp2f(sc[4 * g + 3]);
        uint2 pk;
        pk.x = pkbf(e0, e1);
        pk.y = pkbf(e2, e3);
        *(uint2*)&sh.at.sP[wid][l32 * SPK + g * 8 + half * 4] = pk;
      }
#pragma unroll
      for (int qh = 0; qh < 2; qh++) {
        const frag8 pf = *(const frag8*)&sh.at.sP[wid][(qh * 16 + l16) * SPK + quad16 * 8];
        acc_o[qh] = __builtin_amdgcn_mfma_f32_16x16x32_bf16(vf, pf, acc_o[qh], 0, 0, 0);
        acc_l[qh] = __builtin_amdgcn_mfma_f32_16x16x32_bf16(onef, pf, acc_l[qh], 0, 0, 0);
      }
      kf = kf_n;
      vf = vf_n;
    }

#pragma unroll
    for (int qh = 0; qh < 2; qh++) {
#pragma unroll
      for (int r = 0; r < 4; r++) {
        sh.at.pnum[wid][(quad16 * 4 + r) * 33 + qh * 16 + l16] = acc_o[qh][r];
      }
      if (quad16 == 0) sh.at.pl[wid][qh * 16 + l16] = acc_l[qh][0];
    }
    __syncthreads();
    {
      const int b = bh >> 3, h = bh & 7;
#pragma unroll
      for (int idx = t; idx < 512; idx += 256) {
        const int q16 = idx & 31, d = idx >> 5;
        float num = 0.f, l = 0.f;
#pragma unroll
        for (int w = 0; w < 4; w++) {
          num += sh.at.pnum[w][d * 33 + q16];
          l += sh.at.pl[w][q16];
        }
        AM[((size_t)b * SS + qbase + q16) * DD + d * 8 + h] = f2bf(num / l);
      }
    }
  }
  grid.sync();

  // ---------------- P3: R2 = AMs@w1 + AMc@w2 + b + x_tgt; LN=(R2-m)/var -----
  if ((blockIdx.x & 7) == 0) {
    const int mbase = (blockIdx.x >> 3) * 16;
    const short* W1 = p.wt + 98304;
    const short* W2 = p.wt + 114688;

    floatx4 acc2[2];
    acc2[0] = (floatx4){0.f, 0.f, 0.f, 0.f};
    acc2[1] = (floatx4){0.f, 0.f, 0.f, 0.f};
#pragma unroll
    for (int ks = 0; ks < 4; ks++) {
      const frag8 afS = *(const frag8*)&p.AMs[(size_t)(mbase + l16) * DD + ks * 32 + quad16 * 8];
      const frag8 afC = *(const frag8*)&p.AMc[(size_t)(mbase + l16) * DD + ks * 32 + quad16 * 8];
#pragma unroll
      for (int c = 0; c < 2; c++) {
        const int n0 = (wid * 2 + c) * 16 + l16;
        const frag8 bf1 = *(const frag8*)&W1[n0 * DD + ks * 32 + quad16 * 8];
        const frag8 bf2 = *(const frag8*)&W2[n0 * DD + ks * 32 + quad16 * 8];
        acc2[c] = __builtin_amdgcn_mfma_f32_16x16x32_bf16(afS, bf1, acc2[c], 0, 0, 0);
        acc2[c] = __builtin_amdgcn_mfma_f32_16x16x32_bf16(afC, bf2, acc2[c], 0, 0, 0);
      }
    }

    float v[2][4];
#pragma unroll
    for (int c = 0; c < 2; c++) {
      const int n = wid * 32 + c * 16 + l16;
      const float bn = p.b1[n] + p.b2[n];
#pragma unroll
      for (int r = 0; r < 4; r++) {
        const int m = mbase + quad16 * 4 + r;
        v[c][r] = acc2[c][r] + bn + p.x_tgt[(size_t)m * DD + n];
        p.R2[(size_t)m * DD + n] = v[c][r];
      }
    }

#pragma unroll
    for (int r = 0; r < 4; r++) {
      float s = v[0][r] + v[1][r];
      float sq = v[0][r] * v[0][r] + v[1][r] * v[1][r];
#pragma unroll
      for (int mk = 1; mk < 16; mk <<= 1) {
        s += __shfl_xor(s, mk, 64);
        sq += __shfl_xor(sq, mk, 64);
      }
      if (l16 == 0) {
        sh.tl.sumS[wid][quad16 * 4 + r] = s;
        sh.tl.sumQ[wid][quad16 * 4 + r] = sq;
      }
    }
    __syncthreads();
#pragma unroll
    for (int r = 0; r < 4; r++) {
      const int row = quad16 * 4 + r;
      const float S = sh.tl.sumS[0][row] + sh.tl.sumS[1][row] + sh.tl.sumS[2][row] + sh.tl.sumS[3][row];
      const float Qs_ = sh.tl.sumQ[0][row] + sh.tl.sumQ[1][row] + sh.tl.sumQ[2][row] + sh.tl.sumQ[3][row];
      const float mean = S * (1.0f / 128.0f);
      const float cs = Qs_ - S * mean;
      const float ivar = 127.0f / cs;   // divide by var (faithful quirk)
      const int m = mbase + row;
#pragma unroll
      for (int c = 0; c < 2; c++) {
        const int n = wid * 32 + c * 16 + l16;
        p.LN[(size_t)m * DD + n] = f2bf((v[c][r] - mean) * ivar);
      }
    }
  }
  grid.sync();

  // ---------------- P4: ffn1 h = relu(LN@W3+b3) (1024 single-wave tasks) ----
  {
    const int g = blockIdx.x * 4 + wid;
    if (g < 1024) {
      const int mbase = (g >> 2) * 16;
      const int nblk = (g & 3) * 128;
      const short* W3 = p.wt + 131072;
      floatx4 acc[8];
#pragma unroll
      for (int ct = 0; ct < 8; ct++) acc[ct] = (floatx4){0.f, 0.f, 0.f, 0.f};
#pragma unroll
      for (int ks = 0; ks < 4; ks++) {
        const frag8 af = *(const frag8*)&p.LN[(size_t)(mbase + l16) * DD + ks * 32 + quad16 * 8];
#pragma unroll
        for (int ct = 0; ct < 8; ct++) {
          const frag8 bf = *(const frag8*)&W3[(size_t)(nblk + ct * 16 + l16) * DD + ks * 32 + quad16 * 8];
          acc[ct] = __builtin_amdgcn_mfma_f32_16x16x32_bf16(af, bf, acc[ct], 0, 0, 0);
        }
      }
#pragma unroll
      for (int ct = 0; ct < 8; ct++) {
        const int n = nblk + ct * 16 + l16;
        const float bn = p.b3[n];
#pragma unroll
        for (int r = 0; r < 4; r++) {
          const int m = mbase + quad16 * 4 + r;
          p.Hb[(size_t)m * DF + n] = f2bf(fmaxf(acc[ct][r] + bn, 0.f));
        }
      }
    }
  }
  grid.sync();

  // ---------------- P5: ffn2 out = h@W4 + b4 + R2 (256 spread tasks) --------
  if ((blockIdx.x & 7) == 0 && wid == 0) {
    const int mbase = (blockIdx.x >> 3) * 16;
    const short* W4 = p.wt + 196608;
    floatx4 acc[8];
#pragma unroll
    for (int ct = 0; ct < 8; ct++) acc[ct] = (floatx4){0.f, 0.f, 0.f, 0.f};
#pragma unroll 4
    for (int ks = 0; ks < 16; ks++) {
      const frag8 af = *(const frag8*)&p.Hb[(size_t)(mbase + l16) * DF + ks * 32 + quad16 * 8];
#pragma unroll
      for (int ct = 0; ct < 8; ct++) {
        const frag8 bf = *(const frag8*)&W4[(size_t)(ct * 16 + l16) * DF + ks * 32 + quad16 * 8];
        acc[ct] = __builtin_amdgcn_mfma_f32_16x16x32_bf16(af, bf, acc[ct], 0, 0, 0);
      }
    }
#pragma unroll
    for (int ct = 0; ct < 8; ct++) {
      const int n = ct * 16 + l16;
      const float bn = p.b4[n];
#pragma unroll
      for (int r = 0; r < 4; r++) {
        const int m = mbase + quad16 * 4 + r;
        p.Out[(size_t)m * DD + n] = acc[ct][r] + bn + p.R2[(size_t)m * DD + n];
      }
    }
  }
}

// =====================================================================
// Fallback path: exact r13 kernels (used if cooperative launch fails)
// =====================================================================
struct WSrc { const float* p[10]; };

__global__ __launch_bounds__(256) void wprep_kernel(WSrc w, short* __restrict__ dst) {
  const int wi = blockIdx.y;
  const int kshift = (wi == 9) ? 9 : 7;
  const int N = (wi == 8) ? 512 : 128;
  const int total = N << kshift;
  const int offs[10] = {0, 16384, 32768, 49152, 65536, 81920, 98304, 114688, 131072, 196608};
  const float sc = (wi == 0 || wi == 3) ? 0.25f * 1.4426950408889634f : 1.0f;
  const float* src = w.p[wi];
  short* d = dst + offs[wi];
  const int K = 1 << kshift;
  for (int idx = blockIdx.x * 256 + threadIdx.x; idx < total; idx += gridDim.x * 256) {
    const int n = idx >> kshift, k = idx & (K - 1);
    d[idx] = f2bf(src[k * N + n] * sc);
  }
}

__global__ __launch_bounds__(64) void qkv_kernel(const float* __restrict__ x_tgt,
                                                 const float* __restrict__ enc_out,
                                                 const short* __restrict__ wt,
                                                 short* __restrict__ Qs, short* __restrict__ Ks,
                                                 short* __restrict__ Vts,
                                                 short* __restrict__ Qc, short* __restrict__ Kc,
                                                 short* __restrict__ Vtc) {
  const int lane = threadIdx.x, quad = lane >> 4, l16 = lane & 15;
  const int mbase = blockIdx.x * 16;
  const int which = blockIdx.y;
  const int kind = which % 3;
  const float* A = (which == 3) ? enc_out : x_tgt;
  const short* W = wt + which * 16384;
  short* Qb = (which < 3) ? Qs : Qc;
  short* Kb = (which < 3) ? Ks : Kc;
  short* Vtb = (which < 3) ? Vts : Vtc;

  __shared__ short sC[16 * 130];

  floatx4 acc[8];
#pragma unroll
  for (int ct = 0; ct < 8; ct++) acc[ct] = (floatx4){0.f, 0.f, 0.f, 0.f};
#pragma unroll
  for (int ks = 0; ks < 4; ks++) {
    const float4* ar = (const float4*)&A[(size_t)(mbase + l16) * DD + ks * 32 + quad * 8];
    const frag8 af = cvt8(ar[0], ar[1]);
#pragma unroll
    for (int ct = 0; ct < 8; ct++) {
      const frag8 bf = *(const frag8*)&W[(ct * 16 + l16) * DD + ks * 32 + quad * 8];
      acc[ct] = __builtin_amdgcn_mfma_f32_16x16x32_bf16(af, bf, acc[ct], 0, 0, 0);
    }
  }
#pragma unroll
  for (int ct = 0; ct < 8; ct++) {
#pragma unroll
    for (int r = 0; r < 4; r++) {
      sC[(quad * 4 + r) * 130 + ct * 16 + l16] = f2bf(acc[ct][r]);
    }
  }
  const int b = mbase >> 11;
  const int sbase = mbase & 2047;
  if (kind <= 1) {
    short* Dst = (kind == 0) ? Qb : Kb;
    const int s = lane >> 2, c4 = lane & 3;
#pragma unroll
    for (int h = 0; h < 8; h++) {
      short4 v;
      v.x = sC[s * 130 + (c4 * 4 + 0) * 8 + h];
      v.y = sC[s * 130 + (c4 * 4 + 1) * 8 + h];
      v.z = sC[s * 130 + (c4 * 4 + 2) * 8 + h];
      v.w = sC[s * 130 + (c4 * 4 + 3) * 8 + h];
      const int bh = b * HH + h;
      *(short4*)&Dst[((size_t)bh * SS + sbase + s) * HDIM + c4 * 4] = v;
    }
  } else {
    const int dci = lane >> 2, c4 = lane & 3;
#pragma unroll
    for (int h = 0; h < 8; h++) {
      short4 v;
      v.x = sC[(c4 * 4 + 0) * 130 + dci * 8 + h];
      v.y = sC[(c4 * 4 + 1) * 130 + dci * 8 + h];
      v.z = sC[(c4 * 4 + 2) * 130 + dci * 8 + h];
      v.w = sC[(c4 * 4 + 3) * 130 + dci * 8 + h];
      const int bh = b * HH + h;
      *(short4*)&Vtb[((size_t)bh * HDIM + dci) * SS + sbase + c4 * 4] = v;
    }
  }
}

__global__ __launch_bounds__(256) void attn_mfma_kernel(
    const short* __restrict__ Qa, const short* __restrict__ Ka,
    const short* __restrict__ Vta, short* __restrict__ AMa,
    const short* __restrict__ Qc, const short* __restrict__ Kc,
    const short* __restrict__ Vtc, short* __restrict__ AMc) {
  const int t = threadIdx.x, wid = t >> 6, lane = t & 63;
  const int l32 = lane & 31, half = lane >> 5;
  const int quad = (lane >> 4) & 3, l16 = lane & 15;
  const int bh = blockIdx.y;
  const int qbase = blockIdx.x * 32;
  const int inst = blockIdx.z;
  const short* Q = inst ? Qc : Qa;
  const short* K = inst ? Kc : Ka;
  const short* Vt = inst ? Vtc : Vta;
  short* AM = inst ? AMc : AMa;
  const size_t headoff = (size_t)bh * SS;

  __shared__ short sP[4][32 * SPK];
  __shared__ float pnum[4][16 * 33];
  __shared__ float pl[4][32];

  const frag8 qf = *(const frag8*)&Q[(headoff + qbase + l32) * HDIM + half * 8];
  frag8 onef;
#pragma unroll
  for (int i = 0; i < 8; i++) onef[i] = (short)0x3f80;

  floatx4 acc_o[2], acc_l[2];
  acc_o[0] = (floatx4){0.f, 0.f, 0.f, 0.f}; acc_o[1] = acc_o[0];
  acc_l[0] = acc_o[0]; acc_l[1] = acc_o[0];

  const int keyw = wid * 512;
  const short* Kp = K + (headoff + l32) * HDIM + half * 8;
  const short* Vp = Vt + ((size_t)bh * HDIM + l16) * SS + quad * 8;

  frag8 kf = *(const frag8*)&Kp[(size_t)keyw * HDIM];
  frag8 vf = *(const frag8*)&Vp[keyw];

#pragma unroll 1
  for (int it = 0; it < 16; it++) {
    const int nb = keyw + ((it + 1 < 16) ? (it + 1) : 15) * 32;
    const frag8 kf_n = *(const frag8*)&Kp[(size_t)nb * HDIM];
    const frag8 vf_n = *(const frag8*)&Vp[nb];

    const floatx16 z16 = {0.f};
    const floatx16 sc = __builtin_amdgcn_mfma_f32_32x32x16_bf16(kf, qf, z16, 0, 0, 0);
#pragma unroll
    for (int g = 0; g < 4; g++) {
      const float e0 = __builtin_amdgcn_exp2f(sc[4 * g + 0]);
      const float e1 = __builtin_amdgcn_exp2f(sc[4 * g + 1]);
      const float e2 = __builtin_amdgcn_exp2f(sc[4 * g + 2]);
      const float e3 = __builtin_amdgcn_exp2f(sc[4 * g + 3]);
      uint2 pk;
      pk.x = pkbf(e0, e1);
      pk.y = pkbf(e2, e3);
      *(uint2*)&sP[wid][l32 * SPK + g * 8 + half * 4] = pk;
    }
#pragma unroll
    for (int qh = 0; qh < 2; qh++) {
      const frag8 pf = *(const frag8*)&sP[wid][(qh * 16 + l16) * SPK + quad * 8];
      acc_o[qh] = __builtin_amdgcn_mfma_f32_16x16x32_bf16(vf, pf, acc_o[qh], 0, 0, 0);
      acc_l[qh] = __builtin_amdgcn_mfma_f32_16x16x32_bf16(onef, pf, acc_l[qh], 0, 0, 0);
    }
    kf = kf_n;
    vf = vf_n;
  }

  {
    float* pn = &pnum[wid][0];
    float* plw = &pl[wid][0];
#pragma unroll
    for (int qh = 0; qh < 2; qh++) {
#pragma unroll
      for (int r = 0; r < 4; r++) {
        pn[(quad * 4 + r) * 33 + qh * 16 + l16] = acc_o[qh][r];
      }
      if (quad == 0) plw[qh * 16 + l16] = acc_l[qh][0];
    }
  }
  __syncthreads();
  {
    const int b = bh >> 3, h = bh & 7;
#pragma unroll
    for (int idx = t; idx < 512; idx += 256) {
      const int q16 = idx & 31, d = idx >> 5;
      float num = 0.f, l = 0.f;
#pragma unroll
      for (int w = 0; w < 4; w++) {
        num += pnum[w][d * 33 + q16];
        l += pl[w][q16];
      }
      AM[((size_t)b * SS + qbase + q16) * DD + d * 8 + h] = f2bf(num / l);
    }
  }
}

__global__ __launch_bounds__(256) void tail_kernel(
    const short* __restrict__ AMs, const short* __restrict__ AMc,
    const short* __restrict__ W1, const short* __restrict__ W2,
    const float* __restrict__ b1, const float* __restrict__ b2,
    const float* __restrict__ x_tgt,
    const short* __restrict__ W3, const float* __restrict__ b3,
    const short* __restrict__ W4, const float* __restrict__ b4,
    float* __restrict__ Out) {
  const int t = threadIdx.x, w = t >> 6, lane = t & 63;
  const int quad = lane >> 4, l16 = lane & 15;
  const int mbase = blockIdx.x * 16;

  __shared__ float sumS[4][16];
  __shared__ float sumQ[4][16];
  __shared__ short sLN[16 * LNS];
  __shared__ short hs[16 * HS];

  floatx4 acc2[2];
  acc2[0] = (floatx4){0.f, 0.f, 0.f, 0.f};
  acc2[1] = (floatx4){0.f, 0.f, 0.f, 0.f};
#pragma unroll
  for (int ks = 0; ks < 4; ks++) {
    const frag8 afS = *(const frag8*)&AMs[(size_t)(mbase + l16) * DD + ks * 32 + quad * 8];
    const frag8 afC = *(const frag8*)&AMc[(size_t)(mbase + l16) * DD + ks * 32 + quad * 8];
#pragma unroll
    for (int c = 0; c < 2; c++) {
      const int n0 = (w * 2 + c) * 16 + l16;
      const frag8 bf1 = *(const frag8*)&W1[n0 * DD + ks * 32 + quad * 8];
      const frag8 bf2 = *(const frag8*)&W2[n0 * DD + ks * 32 + quad * 8];
      acc2[c] = __builtin_amdgcn_mfma_f32_16x16x32_bf16(afS, bf1, acc2[c], 0, 0, 0);
      acc2[c] = __builtin_amdgcn_mfma_f32_16x16x32_bf16(afC, bf2, acc2[c], 0, 0, 0);
    }
  }

  float v[2][4];
#pragma unroll
  for (int c = 0; c < 2; c++) {
    const int n = w * 32 + c * 16 + l16;
    const float bn = b1[n] + b2[n];
#pragma unroll
    for (int r = 0; r < 4; r++) {
      const int m = mbase + quad * 4 + r;
      v[c][r] = acc2[c][r] + bn + x_tgt[(size_t)m * DD + n];
    }
  }

#pragma unroll
  for (int r = 0; r < 4; r++) {
    float s = v[0][r] + v[1][r];
    float sq = v[0][r] * v[0][r] + v[1][r] * v[1][r];
#pragma unroll
    for (int mk = 1; mk < 16; mk <<= 1) {
      s += __shfl_xor(s, mk, 64);
      sq += __shfl_xor(sq, mk, 64);
    }
    if (l16 == 0) {
      sumS[w][quad * 4 + r] = s;
      sumQ[w][quad * 4 + r] = sq;
    }
  }
  __syncthreads();

#pragma unroll
  for (int r = 0; r < 4; r++) {
    const int row = quad * 4 + r;
    const float S = sumS[0][row] + sumS[1][row] + sumS[2][row] + sumS[3][row];
    const float Qs_ = sumQ[0][row] + sumQ[1][row] + sumQ[2][row] + sumQ[3][row];
    const float mean = S * (1.0f / 128.0f);
    const float cs = Qs_ - S * mean;
    const float ivar = 127.0f / cs;
#pragma unroll
    for (int c = 0; c < 2; c++) {
      const int n = w * 32 + c * 16 + l16;
      sLN[row * LNS + n] = f2bf((v[c][r] - mean) * ivar);
    }
  }
  __syncthreads();

  {
    floatx4 acc[8];
#pragma unroll
    for (int ct = 0; ct < 8; ct++) acc[ct] = (floatx4){0.f, 0.f, 0.f, 0.f};
    const int nblk = w * 128;
#pragma unroll
    for (int ks = 0; ks < 4; ks++) {
      const frag8 af = *(const frag8*)&sLN[l16 * LNS + ks * 32 + quad * 8];
#pragma unroll
      for (int ct = 0; ct < 8; ct++) {
        const frag8 bf = *(const frag8*)&W3[(size_t)(nblk + ct * 16 + l16) * DD + ks * 32 + quad * 8];
        acc[ct] = __builtin_amdgcn_mfma_f32_16x16x32_bf16(af, bf, acc[ct], 0, 0, 0);
      }
    }
#pragma unroll
    for (int ct = 0; ct < 8; ct++) {
      const int n = nblk + ct * 16 + l16;
      const float bn = b3[n];
#pragma unroll
      for (int r = 0; r < 4; r++) {
        hs[(quad * 4 + r) * HS + n] = f2bf(fmaxf(acc[ct][r] + bn, 0.f));
      }
    }
  }
  __syncthreads();

  {
    floatx4 acc[2];
    acc[0] = (floatx4){0.f, 0.f, 0.f, 0.f};
    acc[1] = (floatx4){0.f, 0.f, 0.f, 0.f};
#pragma unroll 4
    for (int ks = 0; ks < 16; ks++) {
      const frag8 af = *(const frag8*)&hs[l16 * HS + ks * 32 + quad * 8];
#pragma unroll
      for (int c = 0; c < 2; c++) {
        const int n0 = w * 32 + c * 16 + l16;
        const frag8 bf = *(const frag8*)&W4[(size_t)n0 * DF + ks * 32 + quad * 8];
        acc[c] = __builtin_amdgcn_mfma_f32_16x16x32_bf16(af, bf, acc[c], 0, 0, 0);
      }
    }
#pragma unroll
    for (int c = 0; c < 2; c++) {
      const int n = w * 32 + c * 16 + l16;
      const float bn = b4[n];
#pragma unroll
      for (int r = 0; r < 4; r++) {
        const int m = mbase + quad * 4 + r;
        Out[(size_t)m * DD + n] = acc[c][r] + bn + v[c][r];
      }
    }
  }
}

extern "C" void kernel_launch(void* const* d_in, const int* in_sizes, int n_in,
                              void* d_out, int out_size, void* d_ws, size_t ws_size,
                              hipStream_t stream) {
  (void)in_sizes; (void)n_in; (void)out_size; (void)ws_size;
  const float* x_tgt   = (const float*)d_in[0];
  const float* enc_out = (const float*)d_in[1];
  const float* b1 = (const float*)d_in[9];
  const float* b2 = (const float*)d_in[11];
  const float* b3 = (const float*)d_in[13];
  const float* b4 = (const float*)d_in[15];

  // workspace layout (float-slot offsets; bf16 buffers use 2 elems per slot)
  float* ws = (float*)d_ws;
  short* wt   = (short*)(ws + 0);          // 262144 bf16
  short* Qs   = (short*)(ws + 131072);     // each QKV buf: 524288 bf16
  short* Ks   = (short*)(ws + 393216);
  short* Vts  = (short*)(ws + 655360);
  short* AMs  = (short*)(ws + 917504);
  short* Qc   = (short*)(ws + 1179648);
  short* Kc   = (short*)(ws + 1441792);
  short* Vtc  = (short*)(ws + 1703936);
  short* AMc  = (short*)(ws + 1966080);
  float* R2   = ws + 2228224;              // 524288 fp32
  short* LN   = (short*)(ws + 2752512);    // 524288 bf16
  short* Hb   = (short*)(ws + 3014656);    // 2097152 bf16

  Params pp;
  pp.src[0] = (const float*)d_in[2];   // self_wq
  pp.src[1] = (const float*)d_in[3];   // self_wk
  pp.src[2] = (const float*)d_in[4];   // self_wv
  pp.src[3] = (const float*)d_in[5];   // cross_wq
  pp.src[4] = (const float*)d_in[6];   // cross_wk
  pp.src[5] = (const float*)d_in[7];   // cross_wv
  pp.src[6] = (const float*)d_in[8];   // w1
  pp.src[7] = (const float*)d_in[10];  // w2
  pp.src[8] = (const float*)d_in[12];  // w3
  pp.src[9] = (const float*)d_in[14];  // w4
  pp.x_tgt = x_tgt; pp.enc_out = enc_out;
  pp.b1 = b1; pp.b2 = b2; pp.b3 = b3; pp.b4 = b4;
  pp.wt = wt;
  pp.Qs = Qs; pp.Ks = Ks; pp.Vts = Vts; pp.AMs = AMs;
  pp.Qc = Qc; pp.Kc = Kc; pp.Vtc = Vtc; pp.AMc = AMc;
  pp.R2 = R2; pp.LN = LN; pp.Hb = Hb;
  pp.Out = (float*)d_out;

  void* args[] = { &pp };
  hipError_t err = hipLaunchCooperativeKernel((void*)mega_kernel, dim3(GRID), dim3(256),
                                              args, 0, stream);
  if (err == hipSuccess) return;
  (void)hipGetLastError();  // clear error state; fall back to r13 5-launch path

  WSrc wsrc;
  for (int i = 0; i < 10; i++) wsrc.p[i] = pp.src[i];
  const int M = BB * SS;
  const int MT = M / 16;
  wprep_kernel<<<dim3(64, 10), 256, 0, stream>>>(wsrc, wt);
  qkv_kernel<<<dim3(MT, 6), 64, 0, stream>>>(x_tgt, enc_out, wt, Qs, Ks, Vts, Qc, Kc, Vtc);
  attn_mfma_kernel<<<dim3(SS / 32, BB * HH, 2), 256, 0, stream>>>(
      Qs, Ks, Vts, AMs, Qc, Kc, Vtc, AMc);
  tail_kernel<<<MT, 256, 0, stream>>>(AMs, AMc, wt + 98304, wt + 114688,
                                      b1, b2, x_tgt, wt + 131072, b3,
                                      wt + 196608, b4, (float*)d_out);
}

// Round 15
// 146.340 us; speedup vs baseline: 9.2802x; 9.2802x over previous
//
#include <hip/hip_runtime.h>
#include <hip/hip_bf16.h>

// Problem constants
#define BB 2
#define SS 2048
#define DD 128
#define HH 8
#define HDIM 16
#define DF 512
#define SPK 36        // attn P stride (shorts); 72B rows
#define HS 520        // ffn LDS h stride (shorts; %8==0 for b128 alignment)
#define LNS 136       // LN LDS stride (shorts; %8==0 for b128 alignment)

typedef float floatx4 __attribute__((ext_vector_type(4)));
typedef float floatx16 __attribute__((ext_vector_type(16)));
typedef short frag8 __attribute__((ext_vector_type(8)));

__device__ __forceinline__ short f2bf(float x) {
  union { __hip_bfloat16 h; short s; } u;
  u.h = __float2bfloat16(x);
  return u.s;
}
// packed pair convert: v_cvt_pk_bf16_f32
__device__ __forceinline__ unsigned int pkbf(float a, float b) {
  float2 f; f.x = a; f.y = b;
  union { __hip_bfloat162 h2; unsigned int u; } u;
  u.h2 = __float22bfloat162_rn(f);
  return u.u;
}
__device__ __forceinline__ frag8 cvt8(const float4 a, const float4 b) {
  union { frag8 f; unsigned int u[4]; } x;
  x.u[0] = pkbf(a.x, a.y);
  x.u[1] = pkbf(a.z, a.w);
  x.u[2] = pkbf(b.x, b.y);
  x.u[3] = pkbf(b.z, b.w);
  return x.f;
}

// ---------------- weight prep: WT[n][k] bf16, scale folded ----------------
struct WSrc { const float* p[10]; };
// order: self_wq,self_wk,self_wv,cross_wq,cross_wk,cross_wv,w1,w2,w3,w4
__global__ __launch_bounds__(256) void wprep_kernel(WSrc w, short* __restrict__ dst) {
  const int wi = blockIdx.y;
  const int kshift = (wi == 9) ? 9 : 7;          // K: 512 for w4, else 128
  const int N = (wi == 8) ? 512 : 128;           // w3 has N=512
  const int total = N << kshift;
  const int offs[10] = {0, 16384, 32768, 49152, 65536, 81920, 98304, 114688, 131072, 196608};
  // fold 1/sqrt(HD) AND log2(e) into Wq: scores land in log2 domain -> bare v_exp
  const float sc = (wi == 0 || wi == 3) ? 0.25f * 1.4426950408889634f : 1.0f;
  const float* src = w.p[wi];
  short* d = dst + offs[wi];
  const int K = 1 << kshift;
  for (int idx = blockIdx.x * 256 + threadIdx.x; idx < total; idx += gridDim.x * 256) {
    const int n = idx >> kshift, k = idx & (K - 1);
    d[idx] = f2bf(src[k * N + n] * sc);
  }
}

// ---------------- fused 6-way QKV projection (MFMA) ----------------
// grid (M/16, 6), block 64. blockIdx.y: 0..2 self QKV (A=x_tgt),
// 3 cross Q (A=enc_out, quirk), 4..5 cross K/V (A=x_tgt).
__global__ __launch_bounds__(64) void qkv_kernel(const float* __restrict__ x_tgt,
                                                 const float* __restrict__ enc_out,
                                                 const short* __restrict__ wt,
                                                 short* __restrict__ Qs, short* __restrict__ Ks,
                                                 short* __restrict__ Vts,
                                                 short* __restrict__ Qc, short* __restrict__ Kc,
                                                 short* __restrict__ Vtc) {
  const int lane = threadIdx.x, quad = lane >> 4, l16 = lane & 15;
  const int mbase = blockIdx.x * 16;
  const int which = blockIdx.y;
  const int kind = which % 3;  // 0=Q,1=K,2=Vt
  const float* A = (which == 3) ? enc_out : x_tgt;
  const short* W = wt + which * 16384;
  short* Qb = (which < 3) ? Qs : Qc;
  short* Kb = (which < 3) ? Ks : Kc;
  short* Vtb = (which < 3) ? Vts : Vtc;

  __shared__ short sC[16 * 130];  // [m-local][n] bf16, stride 130

  floatx4 acc[8];
#pragma unroll
  for (int ct = 0; ct < 8; ct++) acc[ct] = (floatx4){0.f, 0.f, 0.f, 0.f};

#pragma unroll
  for (int ks = 0; ks < 4; ks++) {
    const float4* ar = (const float4*)&A[(size_t)(mbase + l16) * DD + ks * 32 + quad * 8];
    const frag8 af = cvt8(ar[0], ar[1]);
#pragma unroll
    for (int ct = 0; ct < 8; ct++) {
      const frag8 bf = *(const frag8*)&W[(ct * 16 + l16) * DD + ks * 32 + quad * 8];
      acc[ct] = __builtin_amdgcn_mfma_f32_16x16x32_bf16(af, bf, acc[ct], 0, 0, 0);
    }
  }

#pragma unroll
  for (int ct = 0; ct < 8; ct++) {
#pragma unroll
    for (int r = 0; r < 4; r++) {
      sC[(quad * 4 + r) * 130 + ct * 16 + l16] = f2bf(acc[ct][r]);
    }
  }
  // single wave per block: compiler's lgkmcnt ordering suffices (no barrier)

  const int b = mbase >> 11;
  const int sbase = mbase & 2047;
  if (kind <= 1) {
    short* Dst = (kind == 0) ? Qb : Kb;
    const int s = lane >> 2, c4 = lane & 3;
#pragma unroll
    for (int h = 0; h < 8; h++) {
      short4 v;  // split quirk: n = dci*8 + h
      v.x = sC[s * 130 + (c4 * 4 + 0) * 8 + h];
      v.y = sC[s * 130 + (c4 * 4 + 1) * 8 + h];
      v.z = sC[s * 130 + (c4 * 4 + 2) * 8 + h];
      v.w = sC[s * 130 + (c4 * 4 + 3) * 8 + h];
      const int bh = b * HH + h;
      *(short4*)&Dst[((size_t)bh * SS + sbase + s) * HDIM + c4 * 4] = v;
    }
  } else {
    const int dci = lane >> 2, c4 = lane & 3;
#pragma unroll
    for (int h = 0; h < 8; h++) {
      short4 v;
      v.x = sC[(c4 * 4 + 0) * 130 + dci * 8 + h];
      v.y = sC[(c4 * 4 + 1) * 130 + dci * 8 + h];
      v.z = sC[(c4 * 4 + 2) * 130 + dci * 8 + h];
      v.w = sC[(c4 * 4 + 3) * 130 + dci * 8 + h];
      const int bh = b * HH + h;
      *(short4*)&Vtb[((size_t)bh * HDIM + dci) * SS + sbase + c4 * 4] = v;
    }
  }
}

// ---------------- MFMA flash attention: 32x32x16 QK, split-K 4-wave blocks ----
// grid (SS/32, BB*HH, 2), block 256 = 4 waves; wave w owns keys [w*512, w*512+512).
// Q pre-scaled by 1/sqrt(HD)*log2(e): numerators via bare v_exp_f32.
// DISTANCE-2 SOFTWARE PIPELINE: kf/vf for it+1 and it+2 are in flight; unroll 2
// renames the rotation registers (no v_mov chains) and interleaves body A's
// PV tail with body B's exp chain.
__global__ __launch_bounds__(256) void attn_mfma_kernel(
    const short* __restrict__ Qa, const short* __restrict__ Ka,
    const short* __restrict__ Vta, short* __restrict__ AMa,
    const short* __restrict__ Qc, const short* __restrict__ Kc,
    const short* __restrict__ Vtc, short* __restrict__ AMc) {
  const int t = threadIdx.x, wid = t >> 6, lane = t & 63;
  const int l32 = lane & 31, half = lane >> 5;   // 32-wide frag coords
  const int quad = (lane >> 4) & 3, l16 = lane & 15;
  const int bh = blockIdx.y;
  const int qbase = blockIdx.x * 32;
  const int inst = blockIdx.z;
  const short* Q = inst ? Qc : Qa;
  const short* K = inst ? Kc : Ka;
  const short* Vt = inst ? Vtc : Vta;
  short* AM = inst ? AMc : AMa;
  const size_t headoff = (size_t)bh * SS;

  __shared__ short sP[4][32 * SPK];   // [wave][q][key(32)] bf16
  __shared__ float pnum[4][16 * 33];  // [wave][d*33+q]
  __shared__ float pl[4][32];

  // Q B-frag (32x32x16): n=q=l32, k=half*8+j
  const frag8 qf = *(const frag8*)&Q[(headoff + qbase + l32) * HDIM + half * 8];

  frag8 onef;
#pragma unroll
  for (int i = 0; i < 8; i++) onef[i] = (short)0x3f80;  // bf16 1.0

  floatx4 acc_o[2], acc_l[2];
  acc_o[0] = (floatx4){0.f, 0.f, 0.f, 0.f}; acc_o[1] = acc_o[0];
  acc_l[0] = acc_o[0]; acc_l[1] = acc_o[0];

  const int keyw = wid * 512;
  const short* Kp = K + (headoff + l32) * HDIM + half * 8;   // + key*HDIM
  const short* Vp = Vt + ((size_t)bh * HDIM + l16) * SS + quad * 8;  // + kb

  // pipeline prologue: operands for it=0 and it=1
  frag8 kf0 = *(const frag8*)&Kp[(size_t)keyw * HDIM];
  frag8 vf0 = *(const frag8*)&Vp[keyw];
  frag8 kf1 = *(const frag8*)&Kp[(size_t)(keyw + 32) * HDIM];
  frag8 vf1 = *(const frag8*)&Vp[keyw + 32];

#pragma unroll 2
  for (int it = 0; it < 16; it++) {
    const int nb = keyw + ((it + 2 < 16) ? (it + 2) : 15) * 32;  // clamped prefetch
    const frag8 kf2 = *(const frag8*)&Kp[(size_t)nb * HDIM];
    const frag8 vf2 = *(const frag8*)&Vp[nb];

    const floatx16 z16 = {0.f};
    // C[m=key][n=q]: lane=q, reg r -> key = (r&3)+8*(r>>2)+4*half
    const floatx16 sc = __builtin_amdgcn_mfma_f32_32x32x16_bf16(kf0, qf, z16, 0, 0, 0);
    // bare v_exp + packed cvt: reg group g = keys 8g+4*half+0..3 at fixed q=l32
#pragma unroll
    for (int g = 0; g < 4; g++) {
      const float e0 = __builtin_amdgcn_exp2f(sc[4 * g + 0]);
      const float e1 = __builtin_amdgcn_exp2f(sc[4 * g + 1]);
      const float e2 = __builtin_amdgcn_exp2f(sc[4 * g + 2]);
      const float e3 = __builtin_amdgcn_exp2f(sc[4 * g + 3]);
      uint2 pk;
      pk.x = pkbf(e0, e1);
      pk.y = pkbf(e2, e3);
      *(uint2*)&sP[wid][l32 * SPK + g * 8 + half * 4] = pk;
    }
    // PV (operand-swapped, 16x16x32): C[d][q'] += Vt(16d x 32k) @ P^T(32k x 16q')
#pragma unroll
    for (int qh = 0; qh < 2; qh++) {
      const frag8 pf = *(const frag8*)&sP[wid][(qh * 16 + l16) * SPK + quad * 8];
      acc_o[qh] = __builtin_amdgcn_mfma_f32_16x16x32_bf16(vf0, pf, acc_o[qh], 0, 0, 0);
      acc_l[qh] = __builtin_amdgcn_mfma_f32_16x16x32_bf16(onef, pf, acc_l[qh], 0, 0, 0);
    }
    // rotate the pipeline (renamed away under unroll 2)
    kf0 = kf1; vf0 = vf1;
    kf1 = kf2; vf1 = vf2;
  }

  // stage per-wave partials: acc_o[qh] reg r = num[d=quad*4+r][q=qh*16+l16]
  {
    float* pn = &pnum[wid][0];
    float* plw = &pl[wid][0];
#pragma unroll
    for (int qh = 0; qh < 2; qh++) {
#pragma unroll
      for (int r = 0; r < 4; r++) {
        pn[(quad * 4 + r) * 33 + qh * 16 + l16] = acc_o[qh][r];
      }
      if (quad == 0) plw[qh * 16 + l16] = acc_l[qh][0];  // rows replicated
    }
  }
  __syncthreads();

  {
    const int b = bh >> 3, h = bh & 7;
#pragma unroll
    for (int idx = t; idx < 512; idx += 256) {
      const int q16 = idx & 31, d = idx >> 5;
      float num = 0.f, l = 0.f;
#pragma unroll
      for (int w = 0; w < 4; w++) {
        num += pnum[w][d * 33 + q16];
        l += pl[w][q16];
      }
      AM[((size_t)b * SS + qbase + q16) * DD + d * 8 + h] = f2bf(num / l);
    }
  }
}

// ---------------- fused tail: residual GEMMs + norm + FFN ----------------
// out = relu(LN@W3+b3)@W4 + b4 + R2, where R2 = AMs@w1 + AMc@w2 + b1+b2 + x_tgt
// and LN = (R2-mean)/var. R2/LN never hit global; FFN2 residual = in-register v.
// grid M/16, block 256 = 4 waves; wave w owns out cols [w*32, w*32+32).
__global__ __launch_bounds__(256) void tail_kernel(
    const short* __restrict__ AMs, const short* __restrict__ AMc,
    const short* __restrict__ W1, const short* __restrict__ W2,
    const float* __restrict__ b1, const float* __restrict__ b2,
    const float* __restrict__ x_tgt,
    const short* __restrict__ W3, const float* __restrict__ b3,
    const short* __restrict__ W4, const float* __restrict__ b4,
    float* __restrict__ Out) {
  const int t = threadIdx.x, w = t >> 6, lane = t & 63;
  const int quad = lane >> 4, l16 = lane & 15;
  const int mbase = blockIdx.x * 16;

  __shared__ float sumS[4][16];
  __shared__ float sumQ[4][16];
  __shared__ short sLN[16 * LNS];
  __shared__ short hs[16 * HS];

  // ---- phase A: R2 tile = AMs@W1 + AMc@W2 + b1 + b2 + x_tgt ----
  floatx4 acc2[2];
  acc2[0] = (floatx4){0.f, 0.f, 0.f, 0.f};
  acc2[1] = (floatx4){0.f, 0.f, 0.f, 0.f};
#pragma unroll
  for (int ks = 0; ks < 4; ks++) {
    const frag8 afS = *(const frag8*)&AMs[(size_t)(mbase + l16) * DD + ks * 32 + quad * 8];
    const frag8 afC = *(const frag8*)&AMc[(size_t)(mbase + l16) * DD + ks * 32 + quad * 8];
#pragma unroll
    for (int c = 0; c < 2; c++) {
      const int n0 = (w * 2 + c) * 16 + l16;
      const frag8 bf1 = *(const frag8*)&W1[n0 * DD + ks * 32 + quad * 8];
      const frag8 bf2 = *(const frag8*)&W2[n0 * DD + ks * 32 + quad * 8];
      acc2[c] = __builtin_amdgcn_mfma_f32_16x16x32_bf16(afS, bf1, acc2[c], 0, 0, 0);
      acc2[c] = __builtin_amdgcn_mfma_f32_16x16x32_bf16(afC, bf2, acc2[c], 0, 0, 0);
    }
  }

  float v[2][4];  // R2 values; survive to phase C as the residual
#pragma unroll
  for (int c = 0; c < 2; c++) {
    const int n = w * 32 + c * 16 + l16;
    const float bn = b1[n] + b2[n];
#pragma unroll
    for (int r = 0; r < 4; r++) {
      const int m = mbase + quad * 4 + r;
      v[c][r] = acc2[c][r] + bn + x_tgt[(size_t)m * DD + n];
    }
  }

  // ---- norm: cross-wave row sums ----
#pragma unroll
  for (int r = 0; r < 4; r++) {
    float s = v[0][r] + v[1][r];
    float sq = v[0][r] * v[0][r] + v[1][r] * v[1][r];
#pragma unroll
    for (int mk = 1; mk < 16; mk <<= 1) {
      s += __shfl_xor(s, mk, 64);
      sq += __shfl_xor(sq, mk, 64);
    }
    if (l16 == 0) {
      sumS[w][quad * 4 + r] = s;
      sumQ[w][quad * 4 + r] = sq;
    }
  }
  __syncthreads();

#pragma unroll
  for (int r = 0; r < 4; r++) {
    const int row = quad * 4 + r;
    const float S = sumS[0][row] + sumS[1][row] + sumS[2][row] + sumS[3][row];
    const float Qs_ = sumQ[0][row] + sumQ[1][row] + sumQ[2][row] + sumQ[3][row];
    const float mean = S * (1.0f / 128.0f);
    const float cs = Qs_ - S * mean;        // sum of squared deviations
    const float ivar = 127.0f / cs;         // 1/var, var = cs/127 (faithful quirk)
#pragma unroll
    for (int c = 0; c < 2; c++) {
      const int n = w * 32 + c * 16 + l16;
      sLN[row * LNS + n] = f2bf((v[c][r] - mean) * ivar);
    }
  }
  __syncthreads();

  // ---- phase B: h = relu(LN @ W3 + b3), wave w -> h cols [w*128,(w+1)*128) ----
  {
    floatx4 acc[8];
#pragma unroll
    for (int ct = 0; ct < 8; ct++) acc[ct] = (floatx4){0.f, 0.f, 0.f, 0.f};
    const int nblk = w * 128;
#pragma unroll
    for (int ks = 0; ks < 4; ks++) {
      const frag8 af = *(const frag8*)&sLN[l16 * LNS + ks * 32 + quad * 8];
#pragma unroll
      for (int ct = 0; ct < 8; ct++) {
        const frag8 bf = *(const frag8*)&W3[(size_t)(nblk + ct * 16 + l16) * DD + ks * 32 + quad * 8];
        acc[ct] = __builtin_amdgcn_mfma_f32_16x16x32_bf16(af, bf, acc[ct], 0, 0, 0);
      }
    }
#pragma unroll
    for (int ct = 0; ct < 8; ct++) {
      const int n = nblk + ct * 16 + l16;
      const float bn = b3[n];
#pragma unroll
      for (int r = 0; r < 4; r++) {
        hs[(quad * 4 + r) * HS + n] = f2bf(fmaxf(acc[ct][r] + bn, 0.f));
      }
    }
  }
  __syncthreads();

  // ---- phase C: out = h @ W4 + b4 + v (in-register residual) ----
  {
    floatx4 acc[2];
    acc[0] = (floatx4){0.f, 0.f, 0.f, 0.f};
    acc[1] = (floatx4){0.f, 0.f, 0.f, 0.f};
#pragma unroll 4
    for (int ks = 0; ks < 16; ks++) {
      const frag8 af = *(const frag8*)&hs[l16 * HS + ks * 32 + quad * 8];
#pragma unroll
      for (int c = 0; c < 2; c++) {
        const int n0 = w * 32 + c * 16 + l16;
        const frag8 bf = *(const frag8*)&W4[(size_t)n0 * DF + ks * 32 + quad * 8];
        acc[c] = __builtin_amdgcn_mfma_f32_16x16x32_bf16(af, bf, acc[c], 0, 0, 0);
      }
    }
#pragma unroll
    for (int c = 0; c < 2; c++) {
      const int n = w * 32 + c * 16 + l16;
      const float bn = b4[n];
#pragma unroll
      for (int r = 0; r < 4; r++) {
        const int m = mbase + quad * 4 + r;
        Out[(size_t)m * DD + n] = acc[c][r] + bn + v[c][r];
      }
    }
  }
}

extern "C" void kernel_launch(void* const* d_in, const int* in_sizes, int n_in,
                              void* d_out, int out_size, void* d_ws, size_t ws_size,
                              hipStream_t stream) {
  (void)in_sizes; (void)n_in; (void)out_size; (void)ws_size;
  const float* x_tgt   = (const float*)d_in[0];
  const float* enc_out = (const float*)d_in[1];
  const float* b1 = (const float*)d_in[9];
  const float* b2 = (const float*)d_in[11];
  const float* b3 = (const float*)d_in[13];
  const float* b4 = (const float*)d_in[15];

  WSrc wsrc;
  wsrc.p[0] = (const float*)d_in[2];   // self_wq
  wsrc.p[1] = (const float*)d_in[3];   // self_wk
  wsrc.p[2] = (const float*)d_in[4];   // self_wv
  wsrc.p[3] = (const float*)d_in[5];   // cross_wq
  wsrc.p[4] = (const float*)d_in[6];   // cross_wk
  wsrc.p[5] = (const float*)d_in[7];   // cross_wv
  wsrc.p[6] = (const float*)d_in[8];   // w1
  wsrc.p[7] = (const float*)d_in[10];  // w2
  wsrc.p[8] = (const float*)d_in[12];  // w3
  wsrc.p[9] = (const float*)d_in[14];  // w4

  // workspace layout (float-slot offsets; bf16 buffers use 2 elems per slot)
  float* ws = (float*)d_ws;
  short* wt   = (short*)(ws + 0);          // 262144 bf16 (512 KB)
  short* Qs   = (short*)(ws + 131072);     // each QKV buf: 524288 bf16
  short* Ks   = (short*)(ws + 393216);
  short* Vts  = (short*)(ws + 655360);
  short* AMs  = (short*)(ws + 917504);
  short* Qc   = (short*)(ws + 1179648);
  short* Kc   = (short*)(ws + 1441792);
  short* Vtc  = (short*)(ws + 1703936);
  short* AMc  = (short*)(ws + 1966080);

  const int M = BB * SS;  // 4096
  const int MT = M / 16;  // 256 row-tiles

  wprep_kernel<<<dim3(64, 10), 256, 0, stream>>>(wsrc, wt);

  // all 6 projections in one launch (cross-Q reads enc_out — faithful quirk)
  qkv_kernel<<<dim3(MT, 6), 64, 0, stream>>>(x_tgt, enc_out, wt, Qs, Ks, Vts, Qc, Kc, Vtc);

  // both attentions in one launch; 32-query waves, split-K 4-wave blocks
  attn_mfma_kernel<<<dim3(SS / 32, BB * HH, 2), 256, 0, stream>>>(
      Qs, Ks, Vts, AMs, Qc, Kc, Vtc, AMc);

  // fused tail: residual GEMMs + norm + FFN (R2/LN never hit global)
  tail_kernel<<<MT, 256, 0, stream>>>(AMs, AMc, wt + 98304, wt + 114688,
                                      b1, b2, x_tgt, wt + 131072, b3,
                                      wt + 196608, b4, (float*)d_out);
}

// Round 16
// 145.284 us; speedup vs baseline: 9.3477x; 1.0073x over previous
//
#include <hip/hip_runtime.h>
#include <hip/hip_bf16.h>

// Problem constants
#define BB 2
#define SS 2048
#define DD 128
#define HH 8
#define HDIM 16
#define DF 512
#define SPK 36        // attn P stride (shorts); 72B rows
#define HS 520        // ffn LDS h stride (shorts; %8==0 for b128 alignment)
#define LNS 136       // LN LDS stride (shorts; %8==0 for b128 alignment)

typedef float floatx4 __attribute__((ext_vector_type(4)));
typedef float floatx16 __attribute__((ext_vector_type(16)));
typedef short frag8 __attribute__((ext_vector_type(8)));

__device__ __forceinline__ short f2bf(float x) {
  union { __hip_bfloat16 h; short s; } u;
  u.h = __float2bfloat16(x);
  return u.s;
}
// packed pair convert: v_cvt_pk_bf16_f32
__device__ __forceinline__ unsigned int pkbf(float a, float b) {
  float2 f; f.x = a; f.y = b;
  union { __hip_bfloat162 h2; unsigned int u; } u;
  u.h2 = __float22bfloat162_rn(f);
  return u.u;
}
__device__ __forceinline__ frag8 cvt8(const float4 a, const float4 b) {
  union { frag8 f; unsigned int u[4]; } x;
  x.u[0] = pkbf(a.x, a.y);
  x.u[1] = pkbf(a.z, a.w);
  x.u[2] = pkbf(b.x, b.y);
  x.u[3] = pkbf(b.z, b.w);
  return x.f;
}

// ---------------- weight prep: WT[n][k] bf16, scale folded ----------------
struct WSrc { const float* p[10]; };
// order: self_wq,self_wk,self_wv,cross_wq,cross_wk,cross_wv,w1,w2,w3,w4
__global__ __launch_bounds__(256) void wprep_kernel(WSrc w, short* __restrict__ dst) {
  const int wi = blockIdx.y;
  const int kshift = (wi == 9) ? 9 : 7;          // K: 512 for w4, else 128
  const int N = (wi == 8) ? 512 : 128;           // w3 has N=512
  const int total = N << kshift;
  const int offs[10] = {0, 16384, 32768, 49152, 65536, 81920, 98304, 114688, 131072, 196608};
  // fold 1/sqrt(HD) AND log2(e) into Wq: scores land in log2 domain -> bare v_exp
  const float sc = (wi == 0 || wi == 3) ? 0.25f * 1.4426950408889634f : 1.0f;
  const float* src = w.p[wi];
  short* d = dst + offs[wi];
  const int K = 1 << kshift;
  for (int idx = blockIdx.x * 256 + threadIdx.x; idx < total; idx += gridDim.x * 256) {
    const int n = idx >> kshift, k = idx & (K - 1);
    d[idx] = f2bf(src[k * N + n] * sc);
  }
}

// ---------------- fused 6-way QKV projection (MFMA) ----------------
// grid (M/16, 6), block 64. blockIdx.y: 0..2 self QKV (A=x_tgt),
// 3 cross Q (A=enc_out, quirk), 4..5 cross K/V (A=x_tgt).
__global__ __launch_bounds__(64) void qkv_kernel(const float* __restrict__ x_tgt,
                                                 const float* __restrict__ enc_out,
                                                 const short* __restrict__ wt,
                                                 short* __restrict__ Qs, short* __restrict__ Ks,
                                                 short* __restrict__ Vts,
                                                 short* __restrict__ Qc, short* __restrict__ Kc,
                                                 short* __restrict__ Vtc) {
  const int lane = threadIdx.x, quad = lane >> 4, l16 = lane & 15;
  const int mbase = blockIdx.x * 16;
  const int which = blockIdx.y;
  const int kind = which % 3;  // 0=Q,1=K,2=Vt
  const float* A = (which == 3) ? enc_out : x_tgt;
  const short* W = wt + which * 16384;
  short* Qb = (which < 3) ? Qs : Qc;
  short* Kb = (which < 3) ? Ks : Kc;
  short* Vtb = (which < 3) ? Vts : Vtc;

  __shared__ short sC[16 * 130];  // [m-local][n] bf16, stride 130

  floatx4 acc[8];
#pragma unroll
  for (int ct = 0; ct < 8; ct++) acc[ct] = (floatx4){0.f, 0.f, 0.f, 0.f};

#pragma unroll
  for (int ks = 0; ks < 4; ks++) {
    const float4* ar = (const float4*)&A[(size_t)(mbase + l16) * DD + ks * 32 + quad * 8];
    const frag8 af = cvt8(ar[0], ar[1]);
#pragma unroll
    for (int ct = 0; ct < 8; ct++) {
      const frag8 bf = *(const frag8*)&W[(ct * 16 + l16) * DD + ks * 32 + quad * 8];
      acc[ct] = __builtin_amdgcn_mfma_f32_16x16x32_bf16(af, bf, acc[ct], 0, 0, 0);
    }
  }

#pragma unroll
  for (int ct = 0; ct < 8; ct++) {
#pragma unroll
    for (int r = 0; r < 4; r++) {
      sC[(quad * 4 + r) * 130 + ct * 16 + l16] = f2bf(acc[ct][r]);
    }
  }
  // single wave per block: compiler's lgkmcnt ordering suffices (no barrier)

  const int b = mbase >> 11;
  const int sbase = mbase & 2047;
  if (kind <= 1) {
    short* Dst = (kind == 0) ? Qb : Kb;
    const int s = lane >> 2, c4 = lane & 3;
#pragma unroll
    for (int h = 0; h < 8; h++) {
      short4 v;  // split quirk: n = dci*8 + h
      v.x = sC[s * 130 + (c4 * 4 + 0) * 8 + h];
      v.y = sC[s * 130 + (c4 * 4 + 1) * 8 + h];
      v.z = sC[s * 130 + (c4 * 4 + 2) * 8 + h];
      v.w = sC[s * 130 + (c4 * 4 + 3) * 8 + h];
      const int bh = b * HH + h;
      *(short4*)&Dst[((size_t)bh * SS + sbase + s) * HDIM + c4 * 4] = v;
    }
  } else {
    const int dci = lane >> 2, c4 = lane & 3;
#pragma unroll
    for (int h = 0; h < 8; h++) {
      short4 v;
      v.x = sC[(c4 * 4 + 0) * 130 + dci * 8 + h];
      v.y = sC[(c4 * 4 + 1) * 130 + dci * 8 + h];
      v.z = sC[(c4 * 4 + 2) * 130 + dci * 8 + h];
      v.w = sC[(c4 * 4 + 3) * 130 + dci * 8 + h];
      const int bh = b * HH + h;
      *(short4*)&Vtb[((size_t)bh * HDIM + dci) * SS + sbase + c4 * 4] = v;
    }
  }
}

// ---------------- MFMA flash attention: 32x32x16 QK, split-K 4-wave blocks ----
// grid (SS/32, BB*HH, 2), block 256 = 4 waves; wave w owns keys [w*512, w*512+512).
// Q pre-scaled by 1/sqrt(HD)*log2(e): numerators via bare v_exp_f32.
// SOFTWARE PIPELINE (distance 1, unroll 1 — measured optimum): next iteration's
// kf/vf global loads are issued at the top of the body, so their ~200-cyc L2
// latency is hidden under the exp phase. (unroll 2 / dbuf / shuffle-exchange
// all measured slower — rounds 7, 11, 12, 15.)
__global__ __launch_bounds__(256) void attn_mfma_kernel(
    const short* __restrict__ Qa, const short* __restrict__ Ka,
    const short* __restrict__ Vta, short* __restrict__ AMa,
    const short* __restrict__ Qc, const short* __restrict__ Kc,
    const short* __restrict__ Vtc, short* __restrict__ AMc) {
  const int t = threadIdx.x, wid = t >> 6, lane = t & 63;
  const int l32 = lane & 31, half = lane >> 5;   // 32-wide frag coords
  const int quad = (lane >> 4) & 3, l16 = lane & 15;
  const int bh = blockIdx.y;
  const int qbase = blockIdx.x * 32;
  const int inst = blockIdx.z;
  const short* Q = inst ? Qc : Qa;
  const short* K = inst ? Kc : Ka;
  const short* Vt = inst ? Vtc : Vta;
  short* AM = inst ? AMc : AMa;
  const size_t headoff = (size_t)bh * SS;

  __shared__ short sP[4][32 * SPK];   // [wave][q][key(32)] bf16
  __shared__ float pnum[4][16 * 33];  // [wave][d*33+q]
  __shared__ float pl[4][32];

  // Q B-frag (32x32x16): n=q=l32, k=half*8+j
  const frag8 qf = *(const frag8*)&Q[(headoff + qbase + l32) * HDIM + half * 8];

  frag8 onef;
#pragma unroll
  for (int i = 0; i < 8; i++) onef[i] = (short)0x3f80;  // bf16 1.0

  floatx4 acc_o[2], acc_l[2];
  acc_o[0] = (floatx4){0.f, 0.f, 0.f, 0.f}; acc_o[1] = acc_o[0];
  acc_l[0] = acc_o[0]; acc_l[1] = acc_o[0];

  const int keyw = wid * 512;
  const short* Kp = K + (headoff + l32) * HDIM + half * 8;   // + key*HDIM
  const short* Vp = Vt + ((size_t)bh * HDIM + l16) * SS + quad * 8;  // + kb

  // pipeline prologue: operands for it=0
  frag8 kf = *(const frag8*)&Kp[(size_t)keyw * HDIM];
  frag8 vf = *(const frag8*)&Vp[keyw];

#pragma unroll 1
  for (int it = 0; it < 16; it++) {
    const int nb = keyw + ((it + 1 < 16) ? (it + 1) : 15) * 32;  // clamped prefetch
    // prefetch next iteration's operands (latency hidden under exp phase)
    const frag8 kf_n = *(const frag8*)&Kp[(size_t)nb * HDIM];
    const frag8 vf_n = *(const frag8*)&Vp[nb];

    const floatx16 z16 = {0.f};
    // C[m=key][n=q]: lane=q, reg r -> key = (r&3)+8*(r>>2)+4*half
    const floatx16 sc = __builtin_amdgcn_mfma_f32_32x32x16_bf16(kf, qf, z16, 0, 0, 0);
    // bare v_exp + packed cvt: reg group g = keys 8g+4*half+0..3 at fixed q=l32
#pragma unroll
    for (int g = 0; g < 4; g++) {
      const float e0 = __builtin_amdgcn_exp2f(sc[4 * g + 0]);
      const float e1 = __builtin_amdgcn_exp2f(sc[4 * g + 1]);
      const float e2 = __builtin_amdgcn_exp2f(sc[4 * g + 2]);
      const float e3 = __builtin_amdgcn_exp2f(sc[4 * g + 3]);
      uint2 pk;
      pk.x = pkbf(e0, e1);
      pk.y = pkbf(e2, e3);
      *(uint2*)&sP[wid][l32 * SPK + g * 8 + half * 4] = pk;
    }
    // PV (operand-swapped, 16x16x32): C[d][q'] += Vt(16d x 32k) @ P^T(32k x 16q')
#pragma unroll
    for (int qh = 0; qh < 2; qh++) {
      const frag8 pf = *(const frag8*)&sP[wid][(qh * 16 + l16) * SPK + quad * 8];
      acc_o[qh] = __builtin_amdgcn_mfma_f32_16x16x32_bf16(vf, pf, acc_o[qh], 0, 0, 0);
      acc_l[qh] = __builtin_amdgcn_mfma_f32_16x16x32_bf16(onef, pf, acc_l[qh], 0, 0, 0);
    }
    kf = kf_n;
    vf = vf_n;
  }

  // stage per-wave partials: acc_o[qh] reg r = num[d=quad*4+r][q=qh*16+l16]
  {
    float* pn = &pnum[wid][0];
    float* plw = &pl[wid][0];
#pragma unroll
    for (int qh = 0; qh < 2; qh++) {
#pragma unroll
      for (int r = 0; r < 4; r++) {
        pn[(quad * 4 + r) * 33 + qh * 16 + l16] = acc_o[qh][r];
      }
      if (quad == 0) plw[qh * 16 + l16] = acc_l[qh][0];  // rows replicated
    }
  }
  __syncthreads();

  {
    const int b = bh >> 3, h = bh & 7;
#pragma unroll
    for (int idx = t; idx < 512; idx += 256) {
      const int q16 = idx & 31, d = idx >> 5;
      float num = 0.f, l = 0.f;
#pragma unroll
      for (int w = 0; w < 4; w++) {
        num += pnum[w][d * 33 + q16];
        l += pl[w][q16];
      }
      AM[((size_t)b * SS + qbase + q16) * DD + d * 8 + h] = f2bf(num / l);
    }
  }
}

// ---------------- fused tail: residual GEMMs + norm + FFN ----------------
// out = relu(LN@W3+b3)@W4 + b4 + R2, where R2 = AMs@w1 + AMc@w2 + b1+b2 + x_tgt
// and LN = (R2-mean)/var. R2/LN never hit global; FFN2 residual = in-register v.
// grid M/16, block 256 = 4 waves; wave w owns out cols [w*32, w*32+32).
__global__ __launch_bounds__(256) void tail_kernel(
    const short* __restrict__ AMs, const short* __restrict__ AMc,
    const short* __restrict__ W1, const short* __restrict__ W2,
    const float* __restrict__ b1, const float* __restrict__ b2,
    const float* __restrict__ x_tgt,
    const short* __restrict__ W3, const float* __restrict__ b3,
    const short* __restrict__ W4, const float* __restrict__ b4,
    float* __restrict__ Out) {
  const int t = threadIdx.x, w = t >> 6, lane = t & 63;
  const int quad = lane >> 4, l16 = lane & 15;
  const int mbase = blockIdx.x * 16;

  __shared__ float sumS[4][16];
  __shared__ float sumQ[4][16];
  __shared__ short sLN[16 * LNS];
  __shared__ short hs[16 * HS];

  // ---- phase A: R2 tile = AMs@W1 + AMc@W2 + b1 + b2 + x_tgt ----
  floatx4 acc2[2];
  acc2[0] = (floatx4){0.f, 0.f, 0.f, 0.f};
  acc2[1] = (floatx4){0.f, 0.f, 0.f, 0.f};
#pragma unroll
  for (int ks = 0; ks < 4; ks++) {
    const frag8 afS = *(const frag8*)&AMs[(size_t)(mbase + l16) * DD + ks * 32 + quad * 8];
    const frag8 afC = *(const frag8*)&AMc[(size_t)(mbase + l16) * DD + ks * 32 + quad * 8];
#pragma unroll
    for (int c = 0; c < 2; c++) {
      const int n0 = (w * 2 + c) * 16 + l16;
      const frag8 bf1 = *(const frag8*)&W1[n0 * DD + ks * 32 + quad * 8];
      const frag8 bf2 = *(const frag8*)&W2[n0 * DD + ks * 32 + quad * 8];
      acc2[c] = __builtin_amdgcn_mfma_f32_16x16x32_bf16(afS, bf1, acc2[c], 0, 0, 0);
      acc2[c] = __builtin_amdgcn_mfma_f32_16x16x32_bf16(afC, bf2, acc2[c], 0, 0, 0);
    }
  }

  float v[2][4];  // R2 values; survive to phase C as the residual
#pragma unroll
  for (int c = 0; c < 2; c++) {
    const int n = w * 32 + c * 16 + l16;
    const float bn = b1[n] + b2[n];
#pragma unroll
    for (int r = 0; r < 4; r++) {
      const int m = mbase + quad * 4 + r;
      v[c][r] = acc2[c][r] + bn + x_tgt[(size_t)m * DD + n];
    }
  }

  // ---- norm: cross-wave row sums ----
#pragma unroll
  for (int r = 0; r < 4; r++) {
    float s = v[0][r] + v[1][r];
    float sq = v[0][r] * v[0][r] + v[1][r] * v[1][r];
#pragma unroll
    for (int mk = 1; mk < 16; mk <<= 1) {
      s += __shfl_xor(s, mk, 64);
      sq += __shfl_xor(sq, mk, 64);
    }
    if (l16 == 0) {
      sumS[w][quad * 4 + r] = s;
      sumQ[w][quad * 4 + r] = sq;
    }
  }
  __syncthreads();

#pragma unroll
  for (int r = 0; r < 4; r++) {
    const int row = quad * 4 + r;
    const float S = sumS[0][row] + sumS[1][row] + sumS[2][row] + sumS[3][row];
    const float Qs_ = sumQ[0][row] + sumQ[1][row] + sumQ[2][row] + sumQ[3][row];
    const float mean = S * (1.0f / 128.0f);
    const float cs = Qs_ - S * mean;        // sum of squared deviations
    const float ivar = 127.0f / cs;         // 1/var, var = cs/127 (faithful quirk)
#pragma unroll
    for (int c = 0; c < 2; c++) {
      const int n = w * 32 + c * 16 + l16;
      sLN[row * LNS + n] = f2bf((v[c][r] - mean) * ivar);
    }
  }
  __syncthreads();

  // ---- phase B: h = relu(LN @ W3 + b3), wave w -> h cols [w*128,(w+1)*128) ----
  {
    floatx4 acc[8];
#pragma unroll
    for (int ct = 0; ct < 8; ct++) acc[ct] = (floatx4){0.f, 0.f, 0.f, 0.f};
    const int nblk = w * 128;
#pragma unroll
    for (int ks = 0; ks < 4; ks++) {
      const frag8 af = *(const frag8*)&sLN[l16 * LNS + ks * 32 + quad * 8];
#pragma unroll
      for (int ct = 0; ct < 8; ct++) {
        const frag8 bf = *(const frag8*)&W3[(size_t)(nblk + ct * 16 + l16) * DD + ks * 32 + quad * 8];
        acc[ct] = __builtin_amdgcn_mfma_f32_16x16x32_bf16(af, bf, acc[ct], 0, 0, 0);
      }
    }
#pragma unroll
    for (int ct = 0; ct < 8; ct++) {
      const int n = nblk + ct * 16 + l16;
      const float bn = b3[n];
#pragma unroll
      for (int r = 0; r < 4; r++) {
        hs[(quad * 4 + r) * HS + n] = f2bf(fmaxf(acc[ct][r] + bn, 0.f));
      }
    }
  }
  __syncthreads();

  // ---- phase C: out = h @ W4 + b4 + v (in-register residual) ----
  {
    floatx4 acc[2];
    acc[0] = (floatx4){0.f, 0.f, 0.f, 0.f};
    acc[1] = (floatx4){0.f, 0.f, 0.f, 0.f};
#pragma unroll 4
    for (int ks = 0; ks < 16; ks++) {
      const frag8 af = *(const frag8*)&hs[l16 * HS + ks * 32 + quad * 8];
#pragma unroll
      for (int c = 0; c < 2; c++) {
        const int n0 = w * 32 + c * 16 + l16;
        const frag8 bf = *(const frag8*)&W4[(size_t)n0 * DF + ks * 32 + quad * 8];
        acc[c] = __builtin_amdgcn_mfma_f32_16x16x32_bf16(af, bf, acc[c], 0, 0, 0);
      }
    }
#pragma unroll
    for (int c = 0; c < 2; c++) {
      const int n = w * 32 + c * 16 + l16;
      const float bn = b4[n];
#pragma unroll
      for (int r = 0; r < 4; r++) {
        const int m = mbase + quad * 4 + r;
        Out[(size_t)m * DD + n] = acc[c][r] + bn + v[c][r];
      }
    }
  }
}

extern "C" void kernel_launch(void* const* d_in, const int* in_sizes, int n_in,
                              void* d_out, int out_size, void* d_ws, size_t ws_size,
                              hipStream_t stream) {
  (void)in_sizes; (void)n_in; (void)out_size; (void)ws_size;
  const float* x_tgt   = (const float*)d_in[0];
  const float* enc_out = (const float*)d_in[1];
  const float* b1 = (const float*)d_in[9];
  const float* b2 = (const float*)d_in[11];
  const float* b3 = (const float*)d_in[13];
  const float* b4 = (const float*)d_in[15];

  WSrc wsrc;
  wsrc.p[0] = (const float*)d_in[2];   // self_wq
  wsrc.p[1] = (const float*)d_in[3];   // self_wk
  wsrc.p[2] = (const float*)d_in[4];   // self_wv
  wsrc.p[3] = (const float*)d_in[5];   // cross_wq
  wsrc.p[4] = (const float*)d_in[6];   // cross_wk
  wsrc.p[5] = (const float*)d_in[7];   // cross_wv
  wsrc.p[6] = (const float*)d_in[8];   // w1
  wsrc.p[7] = (const float*)d_in[10];  // w2
  wsrc.p[8] = (const float*)d_in[12];  // w3
  wsrc.p[9] = (const float*)d_in[14];  // w4

  // workspace layout (float-slot offsets; bf16 buffers use 2 elems per slot)
  float* ws = (float*)d_ws;
  short* wt   = (short*)(ws + 0);          // 262144 bf16 (512 KB)
  short* Qs   = (short*)(ws + 131072);     // each QKV buf: 524288 bf16
  short* Ks   = (short*)(ws + 393216);
  short* Vts  = (short*)(ws + 655360);
  short* AMs  = (short*)(ws + 917504);
  short* Qc   = (short*)(ws + 1179648);
  short* Kc   = (short*)(ws + 1441792);
  short* Vtc  = (short*)(ws + 1703936);
  short* AMc  = (short*)(ws + 1966080);

  const int M = BB * SS;  // 4096
  const int MT = M / 16;  // 256 row-tiles

  wprep_kernel<<<dim3(64, 10), 256, 0, stream>>>(wsrc, wt);

  // all 6 projections in one launch (cross-Q reads enc_out — faithful quirk)
  qkv_kernel<<<dim3(MT, 6), 64, 0, stream>>>(x_tgt, enc_out, wt, Qs, Ks, Vts, Qc, Kc, Vtc);

  // both attentions in one launch; 32-query waves, split-K 4-wave blocks
  attn_mfma_kernel<<<dim3(SS / 32, BB * HH, 2), 256, 0, stream>>>(
      Qs, Ks, Vts, AMs, Qc, Kc, Vtc, AMc);

  // fused tail: residual GEMMs + norm + FFN (R2/LN never hit global)
  tail_kernel<<<MT, 256, 0, stream>>>(AMs, AMc, wt + 98304, wt + 114688,
                                      b1, b2, x_tgt, wt + 131072, b3,
                                      wt + 196608, b4, (float*)d_out);
}